// Round 2
// baseline (145.432 us; speedup 1.0000x reference)
//
#include <hip/hip_runtime.h>

// CurvatureLoss3D — R13: hot-loop codegen frozen (R12 macros, 84 VGPR,
// (256,3) bounds). Geometry change only, driven by R12's first real
// counters: VGPR=84 means HW residency is ~5 blocks/CU, but the 720-block
// grid capped occupancy at 20% (grid-limited, VALUBusy 40%). Fix:
//   CZ=10 / NTZ=19  ->  1368 blocks = 5.34/CU, fully resident at the
//   measured VGPR allocation -> ~2x the co-resident waves per SIMD.
// Cost: staging 12 planes per 10 output planes (1.2x vs 1.105x) ->
// FETCH_SIZE +8%, irrelevant at 13% of HBM peak.
// Arithmetic untouched -> bit-identical partials; fused finalize kept.

typedef float v2f __attribute__((ext_vector_type(2)));

constexpr int DIM  = 192;
constexpr int ODIM = 190;
constexpr int TX = 32, TY = 32, CZ = 10;
constexpr int NTX = 6, NTY = 6, NTZ = 19;     // 19*10 = 190 exactly
constexpr int PLANE = DIM * DIM;
constexpr int NBLOCKS = 2 * NTZ * NTY * NTX;  // 1368 = 5.34 blocks/CU

struct Row { v2f A, B, C; };      // A=(r0,r2) B=(r1,r3) C=(r4,r5)
struct Slice {
    Row   r[3];                   // rows y..y+2
    float xmn[4], xmx[4];         // per-voxel-window (3r x 3c) min/max, this plane
};

// global -> tmp regs (stays in flight; consumed 2 phases later)
#define PREF(T4, T2, g) do {                                             \
    const float* base_ = pn + (zbase + (g)) * PLANE;                     \
    _Pragma("unroll")                                                    \
    for (int dy = 0; dy < 3; ++dy) {                                     \
        T4[dy] = *(const float4*)(base_ + yoff[dy] + c4);                \
        T2[dy] = *(const float2*)(base_ + yoff[dy] + c2);                \
    } } while (0)

// tmp regs -> packed slice (+window minmax)
#define UNPACK(S, T4, T2) do {                                           \
    float mn6[6], mx6[6];                                                \
    _Pragma("unroll")                                                    \
    for (int dy = 0; dy < 3; ++dy) {                                     \
        const float4 a = T4[dy]; const float2 b = T2[dy];                \
        (S).r[dy].A = (v2f){a.x, a.z};                                   \
        (S).r[dy].B = (v2f){a.y, a.w};                                   \
        (S).r[dy].C = (v2f){b.x, b.y};                                   \
        if (dy == 0) {                                                   \
            mn6[0] = a.x; mn6[1] = a.y; mn6[2] = a.z;                    \
            mn6[3] = a.w; mn6[4] = b.x; mn6[5] = b.y;                    \
            mx6[0] = a.x; mx6[1] = a.y; mx6[2] = a.z;                    \
            mx6[3] = a.w; mx6[4] = b.x; mx6[5] = b.y;                    \
        } else {                                                         \
            mn6[0] = fminf(mn6[0], a.x); mx6[0] = fmaxf(mx6[0], a.x);    \
            mn6[1] = fminf(mn6[1], a.y); mx6[1] = fmaxf(mx6[1], a.y);    \
            mn6[2] = fminf(mn6[2], a.z); mx6[2] = fmaxf(mx6[2], a.z);    \
            mn6[3] = fminf(mn6[3], a.w); mx6[3] = fmaxf(mx6[3], a.w);    \
            mn6[4] = fminf(mn6[4], b.x); mx6[4] = fmaxf(mx6[4], b.x);    \
            mn6[5] = fminf(mn6[5], b.y); mx6[5] = fmaxf(mx6[5], b.y);    \
        }                                                                \
    }                                                                    \
    _Pragma("unroll")                                                    \
    for (int j = 0; j < 4; ++j) {                                        \
        (S).xmn[j] = fminf(fminf(mn6[j], mn6[j + 1]), mn6[j + 2]);       \
        (S).xmx[j] = fmaxf(fmaxf(mx6[j], mx6[j + 1]), mx6[j + 2]);       \
    } } while (0)

__global__ __launch_bounds__(256, 3) void curv_main(const float* __restrict__ phi,
                                                    double* __restrict__ acc,
                                                    float* __restrict__ out,
                                                    unsigned* __restrict__ ticket,
                                                    int mode) {
    int bx = blockIdx.x;
    const int tx = bx % NTX; bx /= NTX;
    const int ty = bx % NTY; bx /= NTY;
    const int tz = bx % NTZ; bx /= NTZ;
    const int n  = bx;

    const int xbase = tx * TX, ybase = ty * TY, zbase = tz * CZ;
    const int tid = threadIdx.x;
    const int row = tid >> 3;          // output y within tile (0..31)
    const int x0  = (tid & 7) * 4;     // output x within tile (0..28)
    const float* pn = phi + (long long)n * DIM * PLANE;

    // hoisted addresses (zbase+g <= 180+11 = 191: no z clamp needed)
    const int c4 = xbase + x0;                       // <= 188: float4 in-bounds
    int c2t = c4 + 4; if (c2t > DIM - 2) c2t = DIM - 2;
    const int c2 = c2t;
    int yoff[3];
#pragma unroll
    for (int dy = 0; dy < 3; ++dy) {
        int iy = ybase + row + dy; if (iy > DIM - 1) iy = DIM - 1;
        yoff[dy] = iy * DIM;
    }

    float4 tA4[3]; float2 tA2[3];      // ping-pong staging buffers
    float4 tB4[3]; float2 tB2[3];

    float fsp = 0.0f, fsc = 0.0f;
    const float EPSF = 1e-8f;
    const float EPS4 = 4e-8f;           // 4*eps (exact: eps scaled by 2^2)
    const int oy = ybase + row;

    bool vmask[4];
#pragma unroll
    for (int j = 0; j < 4; ++j)
        vmask[j] = (oy < ODIM) && (xbase + x0 + j < ODIM);

    // stride-2 pair k of a row; k is compile-time constant after unroll,
    // so the chain folds to either a stored pair or a 2-mov rebuild.
    auto PK = [](const Row& w, int k) -> v2f {
        return k == 0 ? w.A
             : (k == 1 ? w.B
             : (k == 2 ? (v2f){w.A.y, w.C.x}      // (r2,r4)
                       : (v2f){w.B.y, w.C.y}));   // (r3,r5)
    };

    auto compute = [&](const Slice& s0, const Slice& s1, const Slice& s2) {
        float wmn[4], wmx[4];
#pragma unroll
        for (int j = 0; j < 4; ++j) {
            wmn[j] = fminf(fminf(s0.xmn[j], s1.xmn[j]), s2.xmn[j]);
            wmx[j] = fmaxf(fmaxf(s0.xmx[j], s1.xmx[j]), s2.xmx[j]);
        }

#pragma unroll
        for (int p = 0; p < 2; ++p) {
            const v2f a0 = PK(s0.r[1], p + 1);
            const v2f a2 = PK(s2.r[1], p + 1);
            const v2f b0 = PK(s1.r[0], p + 1);
            const v2f b2 = PK(s1.r[2], p + 1);
            const v2f cc = PK(s1.r[1], p + 1);
            const v2f zm = PK(s1.r[1], p);
            const v2f zp = PK(s1.r[1], p + 2);

            // raw differences: G = 2g, M = 4h_mixed (constants folded, exact)
            v2f Gx = a2 - a0;
            v2f Gy = b2 - b0;
            v2f Gz = zp - zm;

            v2f c2v = 2.0f * cc;
            v2f hxx = a0 - c2v + a2;
            v2f hyy = b0 - c2v + b2;
            v2f hzz = zm - c2v + zp;

            v2f Mxy = PK(s0.r[0], p + 1) - PK(s0.r[2], p + 1)
                    - PK(s2.r[0], p + 1) + PK(s2.r[2], p + 1);
            v2f Mxz = PK(s0.r[1], p) - PK(s0.r[1], p + 2)
                    - PK(s2.r[1], p) + PK(s2.r[1], p + 2);
            v2f Myz = PK(s1.r[0], p) - PK(s1.r[0], p + 2)
                    - PK(s1.r[2], p) + PK(s1.r[2], p + 2);

            v2f Gx2 = Gx * Gx, Gy2 = Gy * Gy, Gz2 = Gz * Gz;
            v2f mag2G = Gx2 + Gy2 + Gz2 + EPS4;      // = 4*(mag2)

            v2f r = (v2f){ __builtin_amdgcn_rsqf(mag2G.x),
                           __builtin_amdgcn_rsqf(mag2G.y) };   // = inv1/2 exactly
            v2f r3 = r * r * r;                       // = inv3/8
            v2f twor3 = r3 + r3;                      // = inv3/4

            v2f crossG = Gx * Gy * Mxy + Gx * Gz * Mxz + Gy * Gz * Myz; // 16*cross

            v2f num1 = Gx2 * (hyy + hzz) + Gy2 * (hxx + hzz) +
                       Gz2 * (hxx + hyy) - 0.5f * crossG;      // 4*num_orig
            v2f mean_c = num1 * twor3;                // bit-exact vs original
            v2f lap   = (hxx + hyy + hzz) * (r + r);
            v2f num2  = Gx2 * hxx + Gy2 * hyy + Gz2 * hzz + 0.5f * crossG;
            v2f quad  = num2 * twor3;
            v2f gauss = lap - quad;

            v2f disc = mean_c * mean_c - gauss;
            v2f sq = (v2f){ sqrtf(fabsf(disc.x) + EPSF),
                            sqrtf(fabsf(disc.y) + EPSF) };
            v2f k1 = mean_c + sq;
            v2f t  = 2.0f * k1;                       // k1/(0.5+1e-8) == 2*k1
            v2f pen2 = t * t - 1.0f;

#pragma unroll
            for (int e = 0; e < 2; ++e) {
                const int j = p + 2 * e;
                float pen = fmaxf(e ? pen2.y : pen2.x, 0.0f);
                if (vmask[j] && (wmn[j] * wmx[j] < 0.0f)) {
                    fsp += pen;
                    fsc += 1.0f;
                }
            }
        }
    };

    Slice s0, s1, s2;

    // ---- prologue: planes 0,1 unpacked; planes 2,3 in flight ----
    PREF(tA4, tA2, 0); PREF(tB4, tB2, 1);
    UNPACK(s0, tA4, tA2); PREF(tA4, tA2, 2);
    UNPACK(s1, tB4, tB2); PREF(tB4, tB2, 3);

    // ---- 10 phases: unpack plane z+2 (2 phases in flight), pref z+4 ----
    UNPACK(s2, tA4, tA2); PREF(tA4, tA2, 4);  compute(s0, s1, s2);   // z = 0
    UNPACK(s0, tB4, tB2); PREF(tB4, tB2, 5);  compute(s1, s2, s0);
    UNPACK(s1, tA4, tA2); PREF(tA4, tA2, 6);  compute(s2, s0, s1);
    UNPACK(s2, tB4, tB2); PREF(tB4, tB2, 7);  compute(s0, s1, s2);
    UNPACK(s0, tA4, tA2); PREF(tA4, tA2, 8);  compute(s1, s2, s0);
    UNPACK(s1, tB4, tB2); PREF(tB4, tB2, 9);  compute(s2, s0, s1);
    UNPACK(s2, tA4, tA2); PREF(tA4, tA2, 10); compute(s0, s1, s2);
    UNPACK(s0, tB4, tB2); PREF(tB4, tB2, 11); compute(s1, s2, s0);   // z = 7
    UNPACK(s1, tA4, tA2);                     compute(s2, s0, s1);   // z = 8
    UNPACK(s2, tB4, tB2);                     compute(s0, s1, s2);   // z = 9

    // ---- reduction (double from here) ----
    double sp = (double)fsp, sc = (double)fsc;
#pragma unroll
    for (int off = 32; off > 0; off >>= 1) {
        sp += __shfl_down(sp, off, 64);
        sc += __shfl_down(sc, off, 64);
    }

    __shared__ double lsp[4], lsc[4];
    __shared__ int is_last;
    const int wave = tid >> 6, lane = tid & 63;
    if (lane == 0) { lsp[wave] = sp; lsc[wave] = sc; }
    __syncthreads();
    if (tid == 0) {
        double tp = lsp[0] + lsp[1] + lsp[2] + lsp[3];
        double tc = lsc[0] + lsc[1] + lsc[2] + lsc[3];
        if (mode) {
            acc[2 * blockIdx.x]     = tp;
            acc[2 * blockIdx.x + 1] = tc;
            __threadfence();                       // release: partials visible
            unsigned prev = atomicAdd(ticket, 1u); // device-scope RMW
            is_last = (prev == (unsigned)(NBLOCKS - 1)) ? 1 : 0;
        } else {
            atomicAdd(&acc[0], tp);
            atomicAdd(&acc[1], tc);
            is_last = 0;
        }
    }
    __syncthreads();

    // ---- fused finalize: last-arriving block reduces all partials in
    //      fixed order (deterministic regardless of which block finalizes) ----
    if (is_last) {
        __threadfence();                           // acquire: see all partials
        double rp = 0.0, rc = 0.0;
        for (int i = tid; i < NBLOCKS; i += 256) {
            rp += acc[2 * i];
            rc += acc[2 * i + 1];
        }
#pragma unroll
        for (int off = 32; off > 0; off >>= 1) {
            rp += __shfl_down(rp, off, 64);
            rc += __shfl_down(rc, off, 64);
        }
        if (lane == 0) { lsp[wave] = rp; lsc[wave] = rc; }
        __syncthreads();
        if (tid == 0) {
            double tp = lsp[0] + lsp[1] + lsp[2] + lsp[3];
            double tc = lsc[0] + lsc[1] + lsc[2] + lsc[3];
            out[0] = (float)(tp / (tc + 1e-8));
        }
    }
}

// fallback only (workspace too small for partials+ticket): acc[0..1] were
// atomically accumulated; just divide.
__global__ void curv_reduce(const double* __restrict__ acc,
                            float* __restrict__ out) {
    if (threadIdx.x == 0)
        out[0] = (float)(acc[0] / (acc[1] + 1e-8));
}

extern "C" void kernel_launch(void* const* d_in, const int* in_sizes, int n_in,
                              void* d_out, int out_size, void* d_ws, size_t ws_size,
                              hipStream_t stream) {
    const float* phi = (const float*)d_in[0];
    float* out = (float*)d_out;
    double* acc = (double*)d_ws;

    const size_t need = (size_t)(2 * NBLOCKS) * sizeof(double) + sizeof(unsigned);
    if (ws_size >= need) {
        unsigned* ticket = (unsigned*)(acc + 2 * NBLOCKS);
        hipMemsetAsync(ticket, 0, sizeof(unsigned), stream);
        curv_main<<<NBLOCKS, 256, 0, stream>>>(phi, acc, out, ticket, 1);
    } else {
        hipMemsetAsync(d_ws, 0, 2 * sizeof(double), stream);
        curv_main<<<NBLOCKS, 256, 0, stream>>>(phi, acc, out, (unsigned*)nullptr, 0);
        curv_reduce<<<1, 256, 0, stream>>>(acc, out);
    }
}

// Round 3
// 124.070 us; speedup vs baseline: 1.1722x; 1.1722x over previous
//
#include <hip/hip_runtime.h>

// CurvatureLoss3D — R14: REVERT hot loop to R11 (best measured: curv_main
// <=42us @ 720 blocks) after R12/R13 post-mortems showed:
//  - R12's PK dedup + 2-deep ping-pong regressed the hot loop 36%
//    (per-use pair rebuild movs on every arithmetic chain; latency cover
//    R11 didn't need).
//  - R13's grid increase didn't raise residency (occupancy 21->25% only)
//    and added 1.9x prologues: 57->85us.
// Kept from R12 (independently verified, bit-exact): fused last-block
// finalize via device-scope ticket — removes the curv_reduce dispatch.
// Structure: (256,3), 720 blocks, CZ=19, packed no-LDS register-sliding,
// pow2-folded arithmetic (bit-identical to reference).

typedef float v2f __attribute__((ext_vector_type(2)));

constexpr int DIM  = 192;
constexpr int ODIM = 190;
constexpr int TX = 32, TY = 32, CZ = 19;
constexpr int NTX = 6, NTY = 6, NTZ = 10;     // 10*19 = 190 exactly
constexpr int PLANE = DIM * DIM;
constexpr int NBLOCKS = 2 * NTZ * NTY * NTX;  // 720 = 2.8 blocks/CU

struct Slice {
    v2f   q[3][4];          // rows y..y+2; q[dy][k] = (r[k], r[k+2])
    float xmn[4], xmx[4];   // per-voxel-window (3 rows x 3 cols) min/max, this plane
};

__global__ __launch_bounds__(256, 3) void curv_main(const float* __restrict__ phi,
                                                    double* __restrict__ acc,
                                                    float* __restrict__ out,
                                                    unsigned* __restrict__ ticket,
                                                    int mode) {
    int bx = blockIdx.x;
    const int tx = bx % NTX; bx /= NTX;
    const int ty = bx % NTY; bx /= NTY;
    const int tz = bx % NTZ; bx /= NTZ;
    const int n  = bx;

    const int xbase = tx * TX, ybase = ty * TY, zbase = tz * CZ;
    const int tid = threadIdx.x;
    const int row = tid >> 3;          // output y within tile (0..31)
    const int x0  = (tid & 7) * 4;     // output x within tile (0..28)
    const float* pn = phi + (long long)n * DIM * PLANE;

    // hoisted addresses (zbase+g <= 171+20 = 191: no z clamp needed)
    const int c4 = xbase + x0;                       // <= 188: float4 in-bounds
    int c2t = c4 + 4; if (c2t > DIM - 2) c2t = DIM - 2;
    const int c2 = c2t;
    int yoff[3];
#pragma unroll
    for (int dy = 0; dy < 3; ++dy) {
        int iy = ybase + row + dy; if (iy > DIM - 1) iy = DIM - 1;
        yoff[dy] = iy * DIM;
    }

    float4 t4[3]; float2 t2[3];
    auto pref = [&](int g) {            // global -> tmp regs, stays in flight
        const float* base = pn + (zbase + g) * PLANE;
#pragma unroll
        for (int dy = 0; dy < 3; ++dy) {
            t4[dy] = *(const float4*)(base + yoff[dy] + c4);
            t2[dy] = *(const float2*)(base + yoff[dy] + c2);
        }
    };

    auto unpack = [&](Slice& s) {       // tmp regs -> packed slice (+window minmax)
        float mn6[6], mx6[6];
#pragma unroll
        for (int dy = 0; dy < 3; ++dy) {
            const float4 a = t4[dy]; const float2 b = t2[dy];
            s.q[dy][0] = (v2f){a.x, a.z};
            s.q[dy][1] = (v2f){a.y, a.w};
            s.q[dy][2] = (v2f){a.z, b.x};
            s.q[dy][3] = (v2f){a.w, b.y};
            if (dy == 0) {
                mn6[0] = a.x; mn6[1] = a.y; mn6[2] = a.z;
                mn6[3] = a.w; mn6[4] = b.x; mn6[5] = b.y;
                mx6[0] = a.x; mx6[1] = a.y; mx6[2] = a.z;
                mx6[3] = a.w; mx6[4] = b.x; mx6[5] = b.y;
            } else {
                mn6[0] = fminf(mn6[0], a.x); mx6[0] = fmaxf(mx6[0], a.x);
                mn6[1] = fminf(mn6[1], a.y); mx6[1] = fmaxf(mx6[1], a.y);
                mn6[2] = fminf(mn6[2], a.z); mx6[2] = fmaxf(mx6[2], a.z);
                mn6[3] = fminf(mn6[3], a.w); mx6[3] = fmaxf(mx6[3], a.w);
                mn6[4] = fminf(mn6[4], b.x); mx6[4] = fmaxf(mx6[4], b.x);
                mn6[5] = fminf(mn6[5], b.y); mx6[5] = fmaxf(mx6[5], b.y);
            }
        }
#pragma unroll
        for (int j = 0; j < 4; ++j) {   // x-collapse: per-voxel 3x3 window, this plane
            s.xmn[j] = fminf(fminf(mn6[j], mn6[j + 1]), mn6[j + 2]);
            s.xmx[j] = fmaxf(fmaxf(mx6[j], mx6[j + 1]), mx6[j + 2]);
        }
    };

    float fsp = 0.0f, fsc = 0.0f;
    const float EPSF = 1e-8f;
    const float EPS4 = 4e-8f;           // 4*eps (exact: eps scaled by 2^2)
    const int oy = ybase + row;

    bool vmask[4];
#pragma unroll
    for (int j = 0; j < 4; ++j)
        vmask[j] = (oy < ODIM) && (xbase + x0 + j < ODIM);

    auto compute = [&](const Slice& s0, const Slice& s1, const Slice& s2) {
        float wmn[4], wmx[4];
#pragma unroll
        for (int j = 0; j < 4; ++j) {
            wmn[j] = fminf(fminf(s0.xmn[j], s1.xmn[j]), s2.xmn[j]);
            wmx[j] = fmaxf(fmaxf(s0.xmx[j], s1.xmx[j]), s2.xmx[j]);
        }

#pragma unroll
        for (int p = 0; p < 2; ++p) {
            // raw differences: G = 2g, M = 4h_mixed (constants folded, exact)
            v2f Gx = s2.q[1][p + 1] - s0.q[1][p + 1];
            v2f Gy = s1.q[2][p + 1] - s1.q[0][p + 1];
            v2f Gz = s1.q[1][p + 2] - s1.q[1][p];

            v2f c2v = 2.0f * s1.q[1][p + 1];
            v2f hxx = s0.q[1][p + 1] - c2v + s2.q[1][p + 1];
            v2f hyy = s1.q[0][p + 1] - c2v + s1.q[2][p + 1];
            v2f hzz = s1.q[1][p] - c2v + s1.q[1][p + 2];

            v2f Mxy = s0.q[0][p + 1] - s0.q[2][p + 1]
                    - s2.q[0][p + 1] + s2.q[2][p + 1];
            v2f Mxz = s0.q[1][p] - s0.q[1][p + 2]
                    - s2.q[1][p] + s2.q[1][p + 2];
            v2f Myz = s1.q[0][p] - s1.q[0][p + 2]
                    - s1.q[2][p] + s1.q[2][p + 2];

            v2f Gx2 = Gx * Gx, Gy2 = Gy * Gy, Gz2 = Gz * Gz;
            v2f mag2G = Gx2 + Gy2 + Gz2 + EPS4;      // = 4*(mag2)

            v2f r = (v2f){ __builtin_amdgcn_rsqf(mag2G.x),
                           __builtin_amdgcn_rsqf(mag2G.y) };   // = inv1/2 exactly
            v2f r3 = r * r * r;                       // = inv3/8
            v2f twor3 = r3 + r3;                      // = inv3/4

            v2f crossG = Gx * Gy * Mxy + Gx * Gz * Mxz + Gy * Gz * Myz; // 16*cross

            v2f num1 = Gx2 * (hyy + hzz) + Gy2 * (hxx + hzz) +
                       Gz2 * (hxx + hyy) - 0.5f * crossG;      // 4*num_orig
            v2f mean_c = num1 * twor3;                // bit-exact vs original
            v2f lap   = (hxx + hyy + hzz) * (r + r);
            v2f num2  = Gx2 * hxx + Gy2 * hyy + Gz2 * hzz + 0.5f * crossG;
            v2f quad  = num2 * twor3;
            v2f gauss = lap - quad;

            v2f disc = mean_c * mean_c - gauss;
            v2f sq = (v2f){ sqrtf(fabsf(disc.x) + EPSF),
                            sqrtf(fabsf(disc.y) + EPSF) };
            v2f k1 = mean_c + sq;
            v2f t  = 2.0f * k1;                       // k1/(0.5+1e-8) == 2*k1
            v2f pen2 = t * t - 1.0f;

#pragma unroll
            for (int e = 0; e < 2; ++e) {
                const int j = p + 2 * e;
                float pen = fmaxf(e ? pen2.y : pen2.x, 0.0f);
                if (vmask[j] && (wmn[j] * wmx[j] < 0.0f)) {
                    fsp += pen;
                    fsc += 1.0f;
                }
            }
        }
    };

    Slice s0, s1, s2;

    // ---- prologue: planes 0,1 unpacked; plane 2 in flight ----
    pref(0); unpack(s0);
    pref(1); unpack(s1);
    pref(2);

    // ---- 19 pipelined phases: unpack plane z+2, prefetch z+3, compute z ----
    unpack(s2); pref(3);  compute(s0, s1, s2);   // z = 0
    unpack(s0); pref(4);  compute(s1, s2, s0);
    unpack(s1); pref(5);  compute(s2, s0, s1);
    unpack(s2); pref(6);  compute(s0, s1, s2);
    unpack(s0); pref(7);  compute(s1, s2, s0);
    unpack(s1); pref(8);  compute(s2, s0, s1);
    unpack(s2); pref(9);  compute(s0, s1, s2);
    unpack(s0); pref(10); compute(s1, s2, s0);
    unpack(s1); pref(11); compute(s2, s0, s1);
    unpack(s2); pref(12); compute(s0, s1, s2);
    unpack(s0); pref(13); compute(s1, s2, s0);
    unpack(s1); pref(14); compute(s2, s0, s1);
    unpack(s2); pref(15); compute(s0, s1, s2);
    unpack(s0); pref(16); compute(s1, s2, s0);
    unpack(s1); pref(17); compute(s2, s0, s1);
    unpack(s2); pref(18); compute(s0, s1, s2);
    unpack(s0); pref(19); compute(s1, s2, s0);
    unpack(s1); pref(20); compute(s2, s0, s1);
    unpack(s2);           compute(s0, s1, s2);   // z = 18

    // ---- reduction (double from here) ----
    double sp = (double)fsp, sc = (double)fsc;
#pragma unroll
    for (int off = 32; off > 0; off >>= 1) {
        sp += __shfl_down(sp, off, 64);
        sc += __shfl_down(sc, off, 64);
    }

    __shared__ double lsp[4], lsc[4];
    __shared__ int is_last;
    const int wave = tid >> 6, lane = tid & 63;
    if (lane == 0) { lsp[wave] = sp; lsc[wave] = sc; }
    __syncthreads();
    if (tid == 0) {
        double tp = lsp[0] + lsp[1] + lsp[2] + lsp[3];
        double tc = lsc[0] + lsc[1] + lsc[2] + lsc[3];
        if (mode) {
            acc[2 * blockIdx.x]     = tp;
            acc[2 * blockIdx.x + 1] = tc;
            __threadfence();                       // release: partials visible
            unsigned prev = atomicAdd(ticket, 1u); // device-scope RMW
            is_last = (prev == (unsigned)(NBLOCKS - 1)) ? 1 : 0;
        } else {
            atomicAdd(&acc[0], tp);
            atomicAdd(&acc[1], tc);
            is_last = 0;
        }
    }
    __syncthreads();

    // ---- fused finalize: last-arriving block reduces all partials in
    //      fixed order (deterministic regardless of which block finalizes) ----
    if (is_last) {
        __threadfence();                           // acquire: see all partials
        double rp = 0.0, rc = 0.0;
        for (int i = tid; i < NBLOCKS; i += 256) {
            rp += acc[2 * i];
            rc += acc[2 * i + 1];
        }
#pragma unroll
        for (int off = 32; off > 0; off >>= 1) {
            rp += __shfl_down(rp, off, 64);
            rc += __shfl_down(rc, off, 64);
        }
        if (lane == 0) { lsp[wave] = rp; lsc[wave] = rc; }
        __syncthreads();
        if (tid == 0) {
            double tp = lsp[0] + lsp[1] + lsp[2] + lsp[3];
            double tc = lsc[0] + lsc[1] + lsc[2] + lsc[3];
            out[0] = (float)(tp / (tc + 1e-8));
        }
    }
}

// fallback only (workspace too small for partials+ticket): acc[0..1] were
// atomically accumulated; just divide.
__global__ void curv_reduce(const double* __restrict__ acc,
                            float* __restrict__ out) {
    if (threadIdx.x == 0)
        out[0] = (float)(acc[0] / (acc[1] + 1e-8));
}

extern "C" void kernel_launch(void* const* d_in, const int* in_sizes, int n_in,
                              void* d_out, int out_size, void* d_ws, size_t ws_size,
                              hipStream_t stream) {
    const float* phi = (const float*)d_in[0];
    float* out = (float*)d_out;
    double* acc = (double*)d_ws;

    const size_t need = (size_t)(2 * NBLOCKS) * sizeof(double) + sizeof(unsigned);
    if (ws_size >= need) {
        unsigned* ticket = (unsigned*)(acc + 2 * NBLOCKS);
        hipMemsetAsync(ticket, 0, sizeof(unsigned), stream);
        curv_main<<<NBLOCKS, 256, 0, stream>>>(phi, acc, out, ticket, 1);
    } else {
        hipMemsetAsync(d_ws, 0, 2 * sizeof(double), stream);
        curv_main<<<NBLOCKS, 256, 0, stream>>>(phi, acc, out, (unsigned*)nullptr, 0);
        curv_reduce<<<1, 256, 0, stream>>>(acc, out);
    }
}

// Round 5
// 110.100 us; speedup vs baseline: 1.3209x; 1.1269x over previous
//
#include <hip/hip_runtime.h>

// CurvatureLoss3D — R16 = R15 resubmitted verbatim (previous round's bench
// failed with "MI355X container failed twice" — infra, not kernel; no
// counters produced, hypothesis still untested).
//
// R15 rationale (from R12/R13/R14 triangulation):
//  - R14 (R11 loop + ticket) == R12 (PK+2deep + ticket) == 57us, while
//    round-0 (R11 loop + separate reduce) was <=42us => the fused
//    last-block finalize (device-scope __threadfence + 720-way single-line
//    atomic across 8 non-coherent XCD L2s) cost ~+17us; hot-loop changes
//    were ~neutral. Fusion removed; separate 1-block reduce (~3-5us)
//    restored.
//  - Hot loop: R11 duplicated-pair unpack (cheap) + the ONE R12 piece
//    never cleanly isolated: 2-deep ping-pong staging (tA/tB). Per-phase
//    wait becomes vmcnt(6) on loads issued two phases (~700cy) earlier
//    instead of vmcnt(0) on loads from one phase (~350cy) ago vs ~900cy
//    HBM latency. +18 VGPR (~72->90): same 65..128 occupancy tier
//    (4 waves/SIMD), no residency change.
// Arithmetic untouched — bit-identical to reference.

typedef float v2f __attribute__((ext_vector_type(2)));

constexpr int DIM  = 192;
constexpr int ODIM = 190;
constexpr int TX = 32, TY = 32, CZ = 19;
constexpr int NTX = 6, NTY = 6, NTZ = 10;     // 10*19 = 190 exactly
constexpr int PLANE = DIM * DIM;
constexpr int NBLOCKS = 2 * NTZ * NTY * NTX;  // 720 = 2.8 blocks/CU

struct Slice {
    v2f   q[3][4];          // rows y..y+2; q[dy][k] = (r[k], r[k+2])
    float xmn[4], xmx[4];   // per-voxel-window (3 rows x 3 cols) min/max, this plane
};

// global -> tmp regs (stays in flight; consumed two phases later)
#define PREF(T4, T2, g) do {                                             \
    const float* base_ = pn + (zbase + (g)) * PLANE;                     \
    _Pragma("unroll")                                                    \
    for (int dy = 0; dy < 3; ++dy) {                                     \
        T4[dy] = *(const float4*)(base_ + yoff[dy] + c4);                \
        T2[dy] = *(const float2*)(base_ + yoff[dy] + c2);                \
    } } while (0)

// tmp regs -> packed slice with duplicated pairs (+window minmax)
#define UNPACK(S, T4, T2) do {                                           \
    float mn6[6], mx6[6];                                                \
    _Pragma("unroll")                                                    \
    for (int dy = 0; dy < 3; ++dy) {                                     \
        const float4 a = T4[dy]; const float2 b = T2[dy];                \
        (S).q[dy][0] = (v2f){a.x, a.z};                                  \
        (S).q[dy][1] = (v2f){a.y, a.w};                                  \
        (S).q[dy][2] = (v2f){a.z, b.x};                                  \
        (S).q[dy][3] = (v2f){a.w, b.y};                                  \
        if (dy == 0) {                                                   \
            mn6[0] = a.x; mn6[1] = a.y; mn6[2] = a.z;                    \
            mn6[3] = a.w; mn6[4] = b.x; mn6[5] = b.y;                    \
            mx6[0] = a.x; mx6[1] = a.y; mx6[2] = a.z;                    \
            mx6[3] = a.w; mx6[4] = b.x; mx6[5] = b.y;                    \
        } else {                                                         \
            mn6[0] = fminf(mn6[0], a.x); mx6[0] = fmaxf(mx6[0], a.x);    \
            mn6[1] = fminf(mn6[1], a.y); mx6[1] = fmaxf(mx6[1], a.y);    \
            mn6[2] = fminf(mn6[2], a.z); mx6[2] = fmaxf(mx6[2], a.z);    \
            mn6[3] = fminf(mn6[3], a.w); mx6[3] = fmaxf(mx6[3], a.w);    \
            mn6[4] = fminf(mn6[4], b.x); mx6[4] = fmaxf(mx6[4], b.x);    \
            mn6[5] = fminf(mn6[5], b.y); mx6[5] = fmaxf(mx6[5], b.y);    \
        }                                                                \
    }                                                                    \
    _Pragma("unroll")                                                    \
    for (int j = 0; j < 4; ++j) {                                        \
        (S).xmn[j] = fminf(fminf(mn6[j], mn6[j + 1]), mn6[j + 2]);       \
        (S).xmx[j] = fmaxf(fmaxf(mx6[j], mx6[j + 1]), mx6[j + 2]);       \
    } } while (0)

__global__ __launch_bounds__(256, 3) void curv_main(const float* __restrict__ phi,
                                                    double* __restrict__ acc,
                                                    int use_partials) {
    int bx = blockIdx.x;
    const int tx = bx % NTX; bx /= NTX;
    const int ty = bx % NTY; bx /= NTY;
    const int tz = bx % NTZ; bx /= NTZ;
    const int n  = bx;

    const int xbase = tx * TX, ybase = ty * TY, zbase = tz * CZ;
    const int tid = threadIdx.x;
    const int row = tid >> 3;          // output y within tile (0..31)
    const int x0  = (tid & 7) * 4;     // output x within tile (0..28)
    const float* pn = phi + (long long)n * DIM * PLANE;

    // hoisted addresses (zbase+g <= 171+20 = 191: no z clamp needed)
    const int c4 = xbase + x0;                       // <= 188: float4 in-bounds
    int c2t = c4 + 4; if (c2t > DIM - 2) c2t = DIM - 2;
    const int c2 = c2t;
    int yoff[3];
#pragma unroll
    for (int dy = 0; dy < 3; ++dy) {
        int iy = ybase + row + dy; if (iy > DIM - 1) iy = DIM - 1;
        yoff[dy] = iy * DIM;
    }

    float4 tA4[3]; float2 tA2[3];      // ping-pong staging buffers
    float4 tB4[3]; float2 tB2[3];

    float fsp = 0.0f, fsc = 0.0f;
    const float EPSF = 1e-8f;
    const float EPS4 = 4e-8f;           // 4*eps (exact: eps scaled by 2^2)
    const int oy = ybase + row;

    bool vmask[4];
#pragma unroll
    for (int j = 0; j < 4; ++j)
        vmask[j] = (oy < ODIM) && (xbase + x0 + j < ODIM);

    auto compute = [&](const Slice& s0, const Slice& s1, const Slice& s2) {
        float wmn[4], wmx[4];
#pragma unroll
        for (int j = 0; j < 4; ++j) {
            wmn[j] = fminf(fminf(s0.xmn[j], s1.xmn[j]), s2.xmn[j]);
            wmx[j] = fmaxf(fmaxf(s0.xmx[j], s1.xmx[j]), s2.xmx[j]);
        }

#pragma unroll
        for (int p = 0; p < 2; ++p) {
            // raw differences: G = 2g, M = 4h_mixed (constants folded, exact)
            v2f Gx = s2.q[1][p + 1] - s0.q[1][p + 1];
            v2f Gy = s1.q[2][p + 1] - s1.q[0][p + 1];
            v2f Gz = s1.q[1][p + 2] - s1.q[1][p];

            v2f c2v = 2.0f * s1.q[1][p + 1];
            v2f hxx = s0.q[1][p + 1] - c2v + s2.q[1][p + 1];
            v2f hyy = s1.q[0][p + 1] - c2v + s1.q[2][p + 1];
            v2f hzz = s1.q[1][p] - c2v + s1.q[1][p + 2];

            v2f Mxy = s0.q[0][p + 1] - s0.q[2][p + 1]
                    - s2.q[0][p + 1] + s2.q[2][p + 1];
            v2f Mxz = s0.q[1][p] - s0.q[1][p + 2]
                    - s2.q[1][p] + s2.q[1][p + 2];
            v2f Myz = s1.q[0][p] - s1.q[0][p + 2]
                    - s1.q[2][p] + s1.q[2][p + 2];

            v2f Gx2 = Gx * Gx, Gy2 = Gy * Gy, Gz2 = Gz * Gz;
            v2f mag2G = Gx2 + Gy2 + Gz2 + EPS4;      // = 4*(mag2)

            v2f r = (v2f){ __builtin_amdgcn_rsqf(mag2G.x),
                           __builtin_amdgcn_rsqf(mag2G.y) };   // = inv1/2 exactly
            v2f r3 = r * r * r;                       // = inv3/8
            v2f twor3 = r3 + r3;                      // = inv3/4

            v2f crossG = Gx * Gy * Mxy + Gx * Gz * Mxz + Gy * Gz * Myz; // 16*cross

            v2f num1 = Gx2 * (hyy + hzz) + Gy2 * (hxx + hzz) +
                       Gz2 * (hxx + hyy) - 0.5f * crossG;      // 4*num_orig
            v2f mean_c = num1 * twor3;                // bit-exact vs original
            v2f lap   = (hxx + hyy + hzz) * (r + r);
            v2f num2  = Gx2 * hxx + Gy2 * hyy + Gz2 * hzz + 0.5f * crossG;
            v2f quad  = num2 * twor3;
            v2f gauss = lap - quad;

            v2f disc = mean_c * mean_c - gauss;
            v2f sq = (v2f){ sqrtf(fabsf(disc.x) + EPSF),
                            sqrtf(fabsf(disc.y) + EPSF) };
            v2f k1 = mean_c + sq;
            v2f t  = 2.0f * k1;                       // k1/(0.5+1e-8) == 2*k1
            v2f pen2 = t * t - 1.0f;

#pragma unroll
            for (int e = 0; e < 2; ++e) {
                const int j = p + 2 * e;
                float pen = fmaxf(e ? pen2.y : pen2.x, 0.0f);
                if (vmask[j] && (wmn[j] * wmx[j] < 0.0f)) {
                    fsp += pen;
                    fsc += 1.0f;
                }
            }
        }
    };

    Slice s0, s1, s2;

    // ---- prologue: planes 0,1 unpacked; planes 2,3 in flight ----
    PREF(tA4, tA2, 0); PREF(tB4, tB2, 1);
    UNPACK(s0, tA4, tA2); PREF(tA4, tA2, 2);
    UNPACK(s1, tB4, tB2); PREF(tB4, tB2, 3);

    // ---- 19 phases: unpack plane z+2 (issued 2 phases ago), pref z+4 ----
    UNPACK(s2, tA4, tA2); PREF(tA4, tA2, 4);  compute(s0, s1, s2);   // z = 0
    UNPACK(s0, tB4, tB2); PREF(tB4, tB2, 5);  compute(s1, s2, s0);
    UNPACK(s1, tA4, tA2); PREF(tA4, tA2, 6);  compute(s2, s0, s1);
    UNPACK(s2, tB4, tB2); PREF(tB4, tB2, 7);  compute(s0, s1, s2);
    UNPACK(s0, tA4, tA2); PREF(tA4, tA2, 8);  compute(s1, s2, s0);
    UNPACK(s1, tB4, tB2); PREF(tB4, tB2, 9);  compute(s2, s0, s1);
    UNPACK(s2, tA4, tA2); PREF(tA4, tA2, 10); compute(s0, s1, s2);
    UNPACK(s0, tB4, tB2); PREF(tB4, tB2, 11); compute(s1, s2, s0);
    UNPACK(s1, tA4, tA2); PREF(tA4, tA2, 12); compute(s2, s0, s1);
    UNPACK(s2, tB4, tB2); PREF(tB4, tB2, 13); compute(s0, s1, s2);
    UNPACK(s0, tA4, tA2); PREF(tA4, tA2, 14); compute(s1, s2, s0);
    UNPACK(s1, tB4, tB2); PREF(tB4, tB2, 15); compute(s2, s0, s1);
    UNPACK(s2, tA4, tA2); PREF(tA4, tA2, 16); compute(s0, s1, s2);
    UNPACK(s0, tB4, tB2); PREF(tB4, tB2, 17); compute(s1, s2, s0);
    UNPACK(s1, tA4, tA2); PREF(tA4, tA2, 18); compute(s2, s0, s1);
    UNPACK(s2, tB4, tB2); PREF(tB4, tB2, 19); compute(s0, s1, s2);
    UNPACK(s0, tA4, tA2); PREF(tA4, tA2, 20); compute(s1, s2, s0);   // z = 16
    UNPACK(s1, tB4, tB2);                     compute(s2, s0, s1);   // z = 17
    UNPACK(s2, tA4, tA2);                     compute(s0, s1, s2);   // z = 18

    // ---- reduction (double from here) ----
    double sp = (double)fsp, sc = (double)fsc;
#pragma unroll
    for (int off = 32; off > 0; off >>= 1) {
        sp += __shfl_down(sp, off, 64);
        sc += __shfl_down(sc, off, 64);
    }

    __shared__ double lsp[4], lsc[4];
    const int wave = tid >> 6, lane = tid & 63;
    if (lane == 0) { lsp[wave] = sp; lsc[wave] = sc; }
    __syncthreads();
    if (tid == 0) {
        double tp = lsp[0] + lsp[1] + lsp[2] + lsp[3];
        double tc = lsc[0] + lsc[1] + lsc[2] + lsc[3];
        if (use_partials) {
            acc[2 * blockIdx.x]     = tp;
            acc[2 * blockIdx.x + 1] = tc;
        } else {
            atomicAdd(&acc[0], tp);
            atomicAdd(&acc[1], tc);
        }
    }
}

__global__ __launch_bounds__(256) void curv_reduce(const double* __restrict__ part,
                                                   int nblocks, int use_partials,
                                                   float* __restrict__ out) {
    double sp = 0.0, sc = 0.0;
    if (use_partials) {
        for (int i = threadIdx.x; i < nblocks; i += 256) {
            sp += part[2 * i];
            sc += part[2 * i + 1];
        }
    } else if (threadIdx.x == 0) {
        sp = part[0]; sc = part[1];
    }
#pragma unroll
    for (int off = 32; off > 0; off >>= 1) {
        sp += __shfl_down(sp, off, 64);
        sc += __shfl_down(sc, off, 64);
    }
    __shared__ double lsp[4], lsc[4];
    const int wave = threadIdx.x >> 6, lane = threadIdx.x & 63;
    if (lane == 0) { lsp[wave] = sp; lsc[wave] = sc; }
    __syncthreads();
    if (threadIdx.x == 0) {
        double tp = lsp[0] + lsp[1] + lsp[2] + lsp[3];
        double tc = lsc[0] + lsc[1] + lsc[2] + lsc[3];
        out[0] = (float)(tp / (tc + 1e-8));
    }
}

extern "C" void kernel_launch(void* const* d_in, const int* in_sizes, int n_in,
                              void* d_out, int out_size, void* d_ws, size_t ws_size,
                              hipStream_t stream) {
    const float* phi = (const float*)d_in[0];
    float* out = (float*)d_out;
    double* acc = (double*)d_ws;

    const int use_partials = (ws_size >= (size_t)(2 * NBLOCKS) * sizeof(double)) ? 1 : 0;
    if (!use_partials) {
        hipMemsetAsync(d_ws, 0, 2 * sizeof(double), stream);
    }

    curv_main<<<NBLOCKS, 256, 0, stream>>>(phi, acc, use_partials);
    curv_reduce<<<1, 256, 0, stream>>>(acc, NBLOCKS, use_partials, out);
}

// Round 6
// 107.587 us; speedup vs baseline: 1.3518x; 1.0234x over previous
//
#include <hip/hip_runtime.h>

// CurvatureLoss3D — R17: R14 hot loop (1-deep staging, 72 VGPR, verified)
// + round-0 two-kernel epilogue (fused ticket costs ~15us — refuted R14).
// Single change: grid geometry 720 -> 1008 blocks (CZ=14, NTZ=14).
// Rationale: VGPR=72 sits in the 65..128 occupancy tier = 4 waves/SIMD =
// 4 blocks/CU capacity (m69 halving model). This re-explains R13: 1368
// blocks > 1024 capacity -> TWO serial rounds (1024+344), hence slower.
// 720 blocks = 2.8/CU leaves 30% of residency idle while the kernel is
// latency-bound (VALUBusy 41%). 1008 = 3.94/CU fills the cap in ONE round.
// 14*14=196>190: pref plane index clamps at 191 (uniform scalar); phases
// with zbase+z >= 190 skip compute via uniform branch (only 36 tz=13
// blocks). Staging 16 planes per 14 outputs (1.14x vs 1.105x): FETCH +3.5%.
// Arithmetic untouched — bit-identical to reference.

typedef float v2f __attribute__((ext_vector_type(2)));

constexpr int DIM  = 192;
constexpr int ODIM = 190;
constexpr int TX = 32, TY = 32, CZ = 14;
constexpr int NTX = 6, NTY = 6, NTZ = 14;     // 14*14 = 196 >= 190 (clamped)
constexpr int PLANE = DIM * DIM;
constexpr int NBLOCKS = 2 * NTZ * NTY * NTX;  // 1008 = 3.94 blocks/CU, one round

struct Slice {
    v2f   q[3][4];          // rows y..y+2; q[dy][k] = (r[k], r[k+2])
    float xmn[4], xmx[4];   // per-voxel-window (3 rows x 3 cols) min/max, this plane
};

__global__ __launch_bounds__(256, 3) void curv_main(const float* __restrict__ phi,
                                                    double* __restrict__ acc,
                                                    int use_partials) {
    int bx = blockIdx.x;
    const int tx = bx % NTX; bx /= NTX;
    const int ty = bx % NTY; bx /= NTY;
    const int tz = bx % NTZ; bx /= NTZ;
    const int n  = bx;

    const int xbase = tx * TX, ybase = ty * TY, zbase = tz * CZ;
    const int tid = threadIdx.x;
    const int row = tid >> 3;          // output y within tile (0..31)
    const int x0  = (tid & 7) * 4;     // output x within tile (0..28)
    const float* pn = phi + (long long)n * DIM * PLANE;

    const int c4 = xbase + x0;                       // <= 188: float4 in-bounds
    int c2t = c4 + 4; if (c2t > DIM - 2) c2t = DIM - 2;
    const int c2 = c2t;
    int yoff[3];
#pragma unroll
    for (int dy = 0; dy < 3; ++dy) {
        int iy = ybase + row + dy; if (iy > DIM - 1) iy = DIM - 1;
        yoff[dy] = iy * DIM;
    }

    float4 t4[3]; float2 t2[3];
    auto pref = [&](int g) {            // global -> tmp regs, stays in flight
        int zp = zbase + g; if (zp > DIM - 1) zp = DIM - 1;   // uniform clamp
        const float* base = pn + zp * PLANE;
#pragma unroll
        for (int dy = 0; dy < 3; ++dy) {
            t4[dy] = *(const float4*)(base + yoff[dy] + c4);
            t2[dy] = *(const float2*)(base + yoff[dy] + c2);
        }
    };

    auto unpack = [&](Slice& s) {       // tmp regs -> packed slice (+window minmax)
        float mn6[6], mx6[6];
#pragma unroll
        for (int dy = 0; dy < 3; ++dy) {
            const float4 a = t4[dy]; const float2 b = t2[dy];
            s.q[dy][0] = (v2f){a.x, a.z};
            s.q[dy][1] = (v2f){a.y, a.w};
            s.q[dy][2] = (v2f){a.z, b.x};
            s.q[dy][3] = (v2f){a.w, b.y};
            if (dy == 0) {
                mn6[0] = a.x; mn6[1] = a.y; mn6[2] = a.z;
                mn6[3] = a.w; mn6[4] = b.x; mn6[5] = b.y;
                mx6[0] = a.x; mx6[1] = a.y; mx6[2] = a.z;
                mx6[3] = a.w; mx6[4] = b.x; mx6[5] = b.y;
            } else {
                mn6[0] = fminf(mn6[0], a.x); mx6[0] = fmaxf(mx6[0], a.x);
                mn6[1] = fminf(mn6[1], a.y); mx6[1] = fmaxf(mx6[1], a.y);
                mn6[2] = fminf(mn6[2], a.z); mx6[2] = fmaxf(mx6[2], a.z);
                mn6[3] = fminf(mn6[3], a.w); mx6[3] = fmaxf(mx6[3], a.w);
                mn6[4] = fminf(mn6[4], b.x); mx6[4] = fmaxf(mx6[4], b.x);
                mn6[5] = fminf(mn6[5], b.y); mx6[5] = fmaxf(mx6[5], b.y);
            }
        }
#pragma unroll
        for (int j = 0; j < 4; ++j) {   // x-collapse: per-voxel 3x3 window, this plane
            s.xmn[j] = fminf(fminf(mn6[j], mn6[j + 1]), mn6[j + 2]);
            s.xmx[j] = fmaxf(fmaxf(mx6[j], mx6[j + 1]), mx6[j + 2]);
        }
    };

    float fsp = 0.0f, fsc = 0.0f;
    const float EPSF = 1e-8f;
    const float EPS4 = 4e-8f;           // 4*eps (exact: eps scaled by 2^2)
    const int oy = ybase + row;

    bool vmask[4];
#pragma unroll
    for (int j = 0; j < 4; ++j)
        vmask[j] = (oy < ODIM) && (xbase + x0 + j < ODIM);

    auto compute = [&](const Slice& s0, const Slice& s1, const Slice& s2) {
        float wmn[4], wmx[4];
#pragma unroll
        for (int j = 0; j < 4; ++j) {
            wmn[j] = fminf(fminf(s0.xmn[j], s1.xmn[j]), s2.xmn[j]);
            wmx[j] = fmaxf(fmaxf(s0.xmx[j], s1.xmx[j]), s2.xmx[j]);
        }

#pragma unroll
        for (int p = 0; p < 2; ++p) {
            // raw differences: G = 2g, M = 4h_mixed (constants folded, exact)
            v2f Gx = s2.q[1][p + 1] - s0.q[1][p + 1];
            v2f Gy = s1.q[2][p + 1] - s1.q[0][p + 1];
            v2f Gz = s1.q[1][p + 2] - s1.q[1][p];

            v2f c2v = 2.0f * s1.q[1][p + 1];
            v2f hxx = s0.q[1][p + 1] - c2v + s2.q[1][p + 1];
            v2f hyy = s1.q[0][p + 1] - c2v + s1.q[2][p + 1];
            v2f hzz = s1.q[1][p] - c2v + s1.q[1][p + 2];

            v2f Mxy = s0.q[0][p + 1] - s0.q[2][p + 1]
                    - s2.q[0][p + 1] + s2.q[2][p + 1];
            v2f Mxz = s0.q[1][p] - s0.q[1][p + 2]
                    - s2.q[1][p] + s2.q[1][p + 2];
            v2f Myz = s1.q[0][p] - s1.q[0][p + 2]
                    - s1.q[2][p] + s1.q[2][p + 2];

            v2f Gx2 = Gx * Gx, Gy2 = Gy * Gy, Gz2 = Gz * Gz;
            v2f mag2G = Gx2 + Gy2 + Gz2 + EPS4;      // = 4*(mag2)

            v2f r = (v2f){ __builtin_amdgcn_rsqf(mag2G.x),
                           __builtin_amdgcn_rsqf(mag2G.y) };   // = inv1/2 exactly
            v2f r3 = r * r * r;                       // = inv3/8
            v2f twor3 = r3 + r3;                      // = inv3/4

            v2f crossG = Gx * Gy * Mxy + Gx * Gz * Mxz + Gy * Gz * Myz; // 16*cross

            v2f num1 = Gx2 * (hyy + hzz) + Gy2 * (hxx + hzz) +
                       Gz2 * (hxx + hyy) - 0.5f * crossG;      // 4*num_orig
            v2f mean_c = num1 * twor3;                // bit-exact vs original
            v2f lap   = (hxx + hyy + hzz) * (r + r);
            v2f num2  = Gx2 * hxx + Gy2 * hyy + Gz2 * hzz + 0.5f * crossG;
            v2f quad  = num2 * twor3;
            v2f gauss = lap - quad;

            v2f disc = mean_c * mean_c - gauss;
            v2f sq = (v2f){ sqrtf(fabsf(disc.x) + EPSF),
                            sqrtf(fabsf(disc.y) + EPSF) };
            v2f k1 = mean_c + sq;
            v2f t  = 2.0f * k1;                       // k1/(0.5+1e-8) == 2*k1
            v2f pen2 = t * t - 1.0f;

#pragma unroll
            for (int e = 0; e < 2; ++e) {
                const int j = p + 2 * e;
                float pen = fmaxf(e ? pen2.y : pen2.x, 0.0f);
                if (vmask[j] && (wmn[j] * wmx[j] < 0.0f)) {
                    fsp += pen;
                    fsc += 1.0f;
                }
            }
        }
    };

    // uniform per-phase z validity (only tz=13 blocks ever skip)
    auto zok = [&](int z) { return (zbase + z) < ODIM; };

    Slice s0, s1, s2;

    // ---- prologue: planes 0,1 unpacked; plane 2 in flight ----
    pref(0); unpack(s0);
    pref(1); unpack(s1);
    pref(2);

    // ---- 14 pipelined phases: unpack plane z+2, prefetch z+3, compute z ----
    unpack(s2); pref(3);  if (zok(0))  compute(s0, s1, s2);
    unpack(s0); pref(4);  if (zok(1))  compute(s1, s2, s0);
    unpack(s1); pref(5);  if (zok(2))  compute(s2, s0, s1);
    unpack(s2); pref(6);  if (zok(3))  compute(s0, s1, s2);
    unpack(s0); pref(7);  if (zok(4))  compute(s1, s2, s0);
    unpack(s1); pref(8);  if (zok(5))  compute(s2, s0, s1);
    unpack(s2); pref(9);  if (zok(6))  compute(s0, s1, s2);
    unpack(s0); pref(10); if (zok(7))  compute(s1, s2, s0);
    unpack(s1); pref(11); if (zok(8))  compute(s2, s0, s1);
    unpack(s2); pref(12); if (zok(9))  compute(s0, s1, s2);
    unpack(s0); pref(13); if (zok(10)) compute(s1, s2, s0);
    unpack(s1); pref(14); if (zok(11)) compute(s2, s0, s1);
    unpack(s2); pref(15); if (zok(12)) compute(s0, s1, s2);
    unpack(s0);           if (zok(13)) compute(s1, s2, s0);

    // ---- reduction (double from here) ----
    double sp = (double)fsp, sc = (double)fsc;
#pragma unroll
    for (int off = 32; off > 0; off >>= 1) {
        sp += __shfl_down(sp, off, 64);
        sc += __shfl_down(sc, off, 64);
    }

    __shared__ double lsp[4], lsc[4];
    const int wave = tid >> 6, lane = tid & 63;
    if (lane == 0) { lsp[wave] = sp; lsc[wave] = sc; }
    __syncthreads();
    if (tid == 0) {
        double tp = lsp[0] + lsp[1] + lsp[2] + lsp[3];
        double tc = lsc[0] + lsc[1] + lsc[2] + lsc[3];
        if (use_partials) {
            acc[2 * blockIdx.x]     = tp;
            acc[2 * blockIdx.x + 1] = tc;
        } else {
            atomicAdd(&acc[0], tp);
            atomicAdd(&acc[1], tc);
        }
    }
}

__global__ __launch_bounds__(256) void curv_reduce(const double* __restrict__ part,
                                                   int nblocks, int use_partials,
                                                   float* __restrict__ out) {
    double sp = 0.0, sc = 0.0;
    if (use_partials) {
        for (int i = threadIdx.x; i < nblocks; i += 256) {
            sp += part[2 * i];
            sc += part[2 * i + 1];
        }
    } else if (threadIdx.x == 0) {
        sp = part[0]; sc = part[1];
    }
#pragma unroll
    for (int off = 32; off > 0; off >>= 1) {
        sp += __shfl_down(sp, off, 64);
        sc += __shfl_down(sc, off, 64);
    }
    __shared__ double lsp[4], lsc[4];
    const int wave = threadIdx.x >> 6, lane = threadIdx.x & 63;
    if (lane == 0) { lsp[wave] = sp; lsc[wave] = sc; }
    __syncthreads();
    if (threadIdx.x == 0) {
        double tp = lsp[0] + lsp[1] + lsp[2] + lsp[3];
        double tc = lsc[0] + lsc[1] + lsc[2] + lsc[3];
        out[0] = (float)(tp / (tc + 1e-8));
    }
}

extern "C" void kernel_launch(void* const* d_in, const int* in_sizes, int n_in,
                              void* d_out, int out_size, void* d_ws, size_t ws_size,
                              hipStream_t stream) {
    const float* phi = (const float*)d_in[0];
    float* out = (float*)d_out;
    double* acc = (double*)d_ws;

    const int use_partials = (ws_size >= (size_t)(2 * NBLOCKS) * sizeof(double)) ? 1 : 0;
    if (!use_partials) {
        hipMemsetAsync(d_ws, 0, 2 * sizeof(double), stream);
    }

    curv_main<<<NBLOCKS, 256, 0, stream>>>(phi, acc, use_partials);
    curv_reduce<<<1, 256, 0, stream>>>(acc, NBLOCKS, use_partials, out);
}